// Round 1
// baseline (524.669 us; speedup 1.0000x reference)
//
#include <hip/hip_runtime.h>
#include <hip/hip_bf16.h>

// Problem constants
// B=128, C=512, H=W=14 -> HW=196, M=B*HW=25088, P=512
#define Bn   128
#define Cn   512
#define HWn  196
#define Mn   25088
#define Pn   512
#define SPLITK 14
#define KCHUNK 1792   // 25088/14
#define KTILES 28     // 1792/64

// ws layout (float offsets)
#define OFF_ASSIGN 0u                  // 25088*512 = 12845056
#define OFF_XNORM  12845056u           // 25088
#define OFF_WNORM  12870144u           // 512
#define OFF_RAW    12870656u           // 128*512 = 65536
#define OFF_MEAN   12936192u           // 512
#define OFF_PART   12936704u           // 14*512*512 = 3670016
// total = 16606720 floats = 66.4 MB

// d_out layout (float offsets)
#define OUT_CAT  0u        // 128*1024
#define OUT_WSUM 131072u   // 512*512
#define OUT_WNUM 393216u   // 512

// ---------------- wnorm: ||w_n||^2 ----------------
__global__ __launch_bounds__(64) void k_wnorm(const float* __restrict__ w,
                                              float* __restrict__ wn) {
    int n = blockIdx.x, l = threadIdx.x;
    const float* p = w + (size_t)n * Cn + l * 8;
    float4 a = *(const float4*)p;
    float4 b = *(const float4*)(p + 4);
    float s = a.x*a.x + a.y*a.y + a.z*a.z + a.w*a.w
            + b.x*b.x + b.y*b.y + b.z*b.z + b.w*b.w;
    #pragma unroll
    for (int o = 32; o > 0; o >>= 1) s += __shfl_down(s, o);
    if (l == 0) wn[n] = s;
}

// ---------------- xnorm: ||x_row||^2 ----------------
__global__ __launch_bounds__(256) void k_xnorm(const float* __restrict__ fm,
                                               float* __restrict__ xn) {
    __shared__ float s[4][64];
    int t = threadIdx.x;
    int hq = t & 63, cg = t >> 6;
    int row = blockIdx.x * 64 + hq;             // < 25088 (392*64)
    int b = row / HWn, hw = row - b * HWn;
    const float* base = fm + (size_t)b * Cn * HWn + hw;
    float acc = 0.f;
    for (int c = cg; c < Cn; c += 4) {
        float v = base[(size_t)c * HWn];
        acc = fmaf(v, v, acc);
    }
    s[cg][hq] = acc;
    __syncthreads();
    if (cg == 0) xn[row] = s[0][hq] + s[1][hq] + s[2][hq] + s[3][hq];
}

// ---------------- GEMM1: dot[m][n] = sum_k x[m][k]*w[n][k] ----------------
// tiles 64x64, BK=32, x[m][k] = fm[b, k, hw]
__global__ __launch_bounds__(256) void k_dot(const float* __restrict__ fm,
                                             const float* __restrict__ w,
                                             float* __restrict__ dot) {
    __shared__ float As[32 * 68];   // [k][bm]
    __shared__ float Ws[32 * 68];   // [k][n]
    const int tid = threadIdx.x;
    const int bm0 = blockIdx.x * 64;
    const int n0  = blockIdx.y * 64;
    const int tm = tid & 15, tn = tid >> 4;
    // A load: float4 along bm (contiguous hw; 4-aligned never crosses b)
    const int bmq  = tid & 15;
    const int krow = tid >> 4;      // 0..15, also +16
    const int rowA = bm0 + 4 * bmq;
    const int bA   = rowA / HWn;
    const int hwA  = rowA - bA * HWn;
    const float* fmA = fm + (size_t)bA * Cn * HWn + hwA;
    // W load: float4 along k
    const int kq   = tid & 7;       // 0..7
    const int nrow = tid >> 3;      // 0..31, also +32
    float acc[4][4] = {};
    for (int k0 = 0; k0 < Cn; k0 += 32) {
        float4 a0 = *(const float4*)(fmA + (size_t)(k0 + krow)      * HWn);
        float4 a1 = *(const float4*)(fmA + (size_t)(k0 + krow + 16) * HWn);
        float4 w0 = *(const float4*)(w + (size_t)(n0 + nrow)      * Cn + k0 + 4 * kq);
        float4 w1 = *(const float4*)(w + (size_t)(n0 + nrow + 32) * Cn + k0 + 4 * kq);
        __syncthreads();
        *(float4*)(As + krow        * 68 + 4 * bmq) = a0;
        *(float4*)(As + (krow + 16) * 68 + 4 * bmq) = a1;
        Ws[(4*kq+0)*68 + nrow] = w0.x;
        Ws[(4*kq+1)*68 + nrow] = w0.y;
        Ws[(4*kq+2)*68 + nrow] = w0.z;
        Ws[(4*kq+3)*68 + nrow] = w0.w;
        Ws[(4*kq+0)*68 + nrow + 32] = w1.x;
        Ws[(4*kq+1)*68 + nrow + 32] = w1.y;
        Ws[(4*kq+2)*68 + nrow + 32] = w1.z;
        Ws[(4*kq+3)*68 + nrow + 32] = w1.w;
        __syncthreads();
        #pragma unroll
        for (int k = 0; k < 32; ++k) {
            float4 a  = *(const float4*)(As + k * 68 + 4 * tm);
            float4 bv = *(const float4*)(Ws + k * 68 + 4 * tn);
            float av[4] = {a.x, a.y, a.z, a.w};
            float bw[4] = {bv.x, bv.y, bv.z, bv.w};
            #pragma unroll
            for (int i = 0; i < 4; ++i)
                #pragma unroll
                for (int j = 0; j < 4; ++j)
                    acc[i][j] = fmaf(av[i], bw[j], acc[i][j]);
        }
    }
    #pragma unroll
    for (int i = 0; i < 4; ++i) {
        float4 o = make_float4(acc[i][0], acc[i][1], acc[i][2], acc[i][3]);
        *(float4*)(dot + (size_t)(bm0 + 4 * tm + i) * Pn + n0 + 4 * tn) = o;
    }
}

// ---------------- reductions for softmax ----------------
__device__ __forceinline__ float blockMin(float v, float* red4) {
    #pragma unroll
    for (int o = 32; o > 0; o >>= 1) v = fminf(v, __shfl_down(v, o));
    int wid = threadIdx.x >> 6;
    if ((threadIdx.x & 63) == 0) red4[wid] = v;
    __syncthreads();
    float r = fminf(fminf(red4[0], red4[1]), fminf(red4[2], red4[3]));
    __syncthreads();
    return r;
}
__device__ __forceinline__ float blockSum(float v, float* red4) {
    #pragma unroll
    for (int o = 32; o > 0; o >>= 1) v += __shfl_down(v, o);
    int wid = threadIdx.x >> 6;
    if ((threadIdx.x & 63) == 0) red4[wid] = v;
    __syncthreads();
    float r = red4[0] + red4[1] + red4[2] + red4[3];
    __syncthreads();
    return r;
}

// ---------------- softmax + threshold (in place over dot buffer) ----------
__global__ __launch_bounds__(256) void k_softmax(float* __restrict__ da,
                                                 const float* __restrict__ xnorm,
                                                 const float* __restrict__ wnorm) {
    __shared__ float red4[4];
    const float invP = 1.0f / 512.0f;
    int t = threadIdx.x;
    int bm0 = blockIdx.x * 4;
    float wn0 = wnorm[t], wn1 = wnorm[t + 256];
    float d[4][2];
    #pragma unroll
    for (int r = 0; r < 4; ++r) {
        float xnv = xnorm[bm0 + r];
        size_t base = (size_t)(bm0 + r) * Pn;
        d[r][0] = xnv + wn0 - 2.0f * da[base + t];
        d[r][1] = xnv + wn1 - 2.0f * da[base + t + 256];
    }
    #pragma unroll
    for (int r = 0; r < 4; ++r) {
        float dmin = blockMin(fminf(d[r][0], d[r][1]), red4);
        float e0 = __expf(dmin - d[r][0]);
        float e1 = __expf(dmin - d[r][1]);
        float S = blockSum(e0 + e1, red4);
        float inv = 1.0f / S;
        float a0 = e0 * inv, a1 = e1 * inv;
        if (a0 < invP) a0 = 0.0f;
        if (a1 < invP) a1 = 0.0f;
        size_t base = (size_t)(bm0 + r) * Pn;
        da[base + t] = a0;
        da[base + t + 256] = a1;
    }
}

// ---------------- raw[b][p] = sum_m assign[b,m,p] ----------------
__global__ __launch_bounds__(128) void k_asum(const float* __restrict__ assign,
                                              float* __restrict__ raw) {
    int b = blockIdx.x;
    int n = blockIdx.y * 128 + threadIdx.x;
    const float* p = assign + (size_t)b * HWn * Pn + n;
    float s = 0.f;
    for (int m = 0; m < HWn; ++m) s += p[(size_t)m * Pn];
    raw[b * Pn + n] = s;
}

// ---------------- assign_mean + new_w_ep_num ----------------
__global__ __launch_bounds__(256) void k_reduce(const float* __restrict__ raw,
                                                const float* __restrict__ wnum,
                                                float* __restrict__ mean,
                                                float* __restrict__ outnum) {
    int n = blockIdx.x * 256 + threadIdx.x;
    float s = 0.f;
    for (int b = 0; b < Bn; ++b) s += raw[(size_t)b * Pn + n];
    mean[n] = s;
    outnum[n] = wnum[n] + (s > 1.0f ? s : 0.0f);
}

// ---------------- cvec + concat ----------------
__global__ __launch_bounds__(256) void k_cvec(const float* __restrict__ raw,
                                              const float* __restrict__ w,
                                              const float* __restrict__ emb,
                                              const int* __restrict__ epoch,
                                              float* __restrict__ out) {
    __shared__ float srow[512];
    int b = blockIdx.x, t = threadIdx.x;
    srow[t]       = raw[(size_t)b * Pn + t];
    srow[t + 256] = raw[(size_t)b * Pn + t + 256];
    __syncthreads();
    float a0 = 0.f, a1 = 0.f;
    for (int p = 0; p < Pn; ++p) {
        float ap = srow[p];
        a0 = fmaf(ap, w[(size_t)p * Cn + t], a0);
        a1 = fmaf(ap, w[(size_t)p * Cn + t + 256], a1);
    }
    const float sc = 1.0f / (196.0f * 512.0f);
    int ep = epoch[0];
    float c0 = (ep > 2) ? fmaxf(a0, 0.f) * sc : 0.f;
    float c1 = (ep > 2) ? fmaxf(a1, 0.f) * sc : 0.f;
    out[(size_t)b * 1024 + t]             = emb[(size_t)b * Cn + t];
    out[(size_t)b * 1024 + t + 256]       = emb[(size_t)b * Cn + t + 256];
    out[(size_t)b * 1024 + 512 + t]       = c0;
    out[(size_t)b * 1024 + 512 + t + 256] = c1;
}

// ---------------- GEMM2: update_w[n][c] = sum_bm assign[bm][n]*x[bm][c] ---
// split-K partials, tiles 64x64, BK=64
__global__ __launch_bounds__(256) void k_upw(const float* __restrict__ assign,
                                             const float* __restrict__ fm,
                                             float* __restrict__ part) {
    __shared__ float As[64 * 68];   // [bm][n]
    __shared__ float Bs[64 * 68];   // [bm][c]
    const int tid = threadIdx.x;
    const int n0 = blockIdx.x * 64;
    const int c0 = blockIdx.y * 64;
    const int sp = blockIdx.z;
    const int tn = tid & 15, tc = tid >> 4;
    const int nq   = tid & 15;   // A: float4 along n
    const int bmrA = tid >> 4;   // A: bm row 0..15 (+16j)
    const int bmq  = tid & 15;   // B: float4 along bm
    const int cr   = tid >> 4;   // B: c 0..15 (+16j)
    float acc[4][4] = {};
    const int bmStart = sp * KCHUNK;
    for (int tt = 0; tt < KTILES; ++tt) {
        const int bm0 = bmStart + tt * 64;
        float4 av[4];
        #pragma unroll
        for (int j = 0; j < 4; ++j)
            av[j] = *(const float4*)(assign + (size_t)(bm0 + bmrA + 16 * j) * Pn + n0 + 4 * nq);
        const int rowB = bm0 + 4 * bmq;
        const int bB = rowB / HWn;
        const int hwB = rowB - bB * HWn;
        float4 bvv[4];
        #pragma unroll
        for (int j = 0; j < 4; ++j)
            bvv[j] = *(const float4*)(fm + (size_t)(bB * Cn + c0 + cr + 16 * j) * HWn + hwB);
        __syncthreads();
        #pragma unroll
        for (int j = 0; j < 4; ++j)
            *(float4*)(As + (bmrA + 16 * j) * 68 + 4 * nq) = av[j];
        #pragma unroll
        for (int j = 0; j < 4; ++j) {
            Bs[(4*bmq+0)*68 + cr + 16*j] = bvv[j].x;
            Bs[(4*bmq+1)*68 + cr + 16*j] = bvv[j].y;
            Bs[(4*bmq+2)*68 + cr + 16*j] = bvv[j].z;
            Bs[(4*bmq+3)*68 + cr + 16*j] = bvv[j].w;
        }
        __syncthreads();
        #pragma unroll
        for (int k = 0; k < 64; ++k) {
            float4 a = *(const float4*)(As + k * 68 + 4 * tn);
            float4 b = *(const float4*)(Bs + k * 68 + 4 * tc);
            float an[4] = {a.x, a.y, a.z, a.w};
            float bc[4] = {b.x, b.y, b.z, b.w};
            #pragma unroll
            for (int i = 0; i < 4; ++i)
                #pragma unroll
                for (int j = 0; j < 4; ++j)
                    acc[i][j] = fmaf(an[i], bc[j], acc[i][j]);
        }
    }
    float* o = part + (size_t)sp * (Pn * Cn);
    #pragma unroll
    for (int i = 0; i < 4; ++i) {
        float4 v = make_float4(acc[i][0], acc[i][1], acc[i][2], acc[i][3]);
        *(float4*)(o + (size_t)(n0 + 4 * tn + i) * Cn + c0 + 4 * tc) = v;
    }
}

// ---------------- epilogue: new_w_ep_sum ----------------
__global__ __launch_bounds__(256) void k_wep(const float* __restrict__ part,
                                             const float* __restrict__ mean,
                                             const float* __restrict__ wsum,
                                             float* __restrict__ out1) {
    int n = blockIdx.x, t = threadIdx.x;
    bool upd = mean[n] > 1.0f;
    #pragma unroll
    for (int cc = 0; cc < 2; ++cc) {
        int c = t + cc * 256;
        float s = 0.f;
        #pragma unroll
        for (int k = 0; k < SPLITK; ++k)
            s += part[(size_t)k * (Pn * Cn) + (size_t)n * Cn + c];
        size_t idx = (size_t)n * Cn + c;
        out1[idx] = wsum[idx] + (upd ? s : 0.f);
    }
}

extern "C" void kernel_launch(void* const* d_in, const int* in_sizes, int n_in,
                              void* d_out, int out_size, void* d_ws, size_t ws_size,
                              hipStream_t stream) {
    const float* fm    = (const float*)d_in[0];
    const float* emb   = (const float*)d_in[1];
    const float* w     = (const float*)d_in[2];
    const float* wsum  = (const float*)d_in[3];
    const float* wnum  = (const float*)d_in[4];
    const int*   epoch = (const int*)d_in[5];
    float* out = (float*)d_out;
    float* wsf = (float*)d_ws;

    float* assignb = wsf + OFF_ASSIGN;
    float* xnormb  = wsf + OFF_XNORM;
    float* wnormb  = wsf + OFF_WNORM;
    float* rawb    = wsf + OFF_RAW;
    float* meanb   = wsf + OFF_MEAN;
    float* partb   = wsf + OFF_PART;

    k_wnorm<<<512, 64, 0, stream>>>(w, wnormb);
    k_xnorm<<<392, 256, 0, stream>>>(fm, xnormb);
    k_dot<<<dim3(Mn / 64, Pn / 64), 256, 0, stream>>>(fm, w, assignb);
    k_softmax<<<Mn / 4, 256, 0, stream>>>(assignb, xnormb, wnormb);
    k_asum<<<dim3(Bn, 4), 128, 0, stream>>>(assignb, rawb);
    k_reduce<<<2, 256, 0, stream>>>(rawb, wnum, meanb, out + OUT_WNUM);
    k_cvec<<<Bn, 256, 0, stream>>>(rawb, w, emb, epoch, out + OUT_CAT);
    k_upw<<<dim3(Pn / 64, Cn / 64, SPLITK), 256, 0, stream>>>(assignb, fm, partb);
    k_wep<<<Pn, 256, 0, stream>>>(partb, meanb, wsum, out + OUT_WSUM);
}

// Round 3
// 381.337 us; speedup vs baseline: 1.3759x; 1.3759x over previous
//
#include <hip/hip_runtime.h>
#include <hip/hip_bf16.h>

// Problem constants
// B=128, C=512, H=W=14 -> HW=196, M=B*HW=25088, P=512
#define Bn   128
#define Cn   512
#define HWn  196
#define Mn   25088
#define Pn   512
#define SPLITK 49          // GEMM2 split-K chunks of 512 m each

// ws layout (float offsets)
#define OFF_ASSIGN 0u                  // 25088*512 fp32 = 12845056 floats
#define OFF_PART   0u                  // 49*512*512 fp32 = 12845056 floats (alias, used after asum/tr)
#define OFF_XNORM  12845056u           // 25088
#define OFF_WNORM  12870144u           // 512
#define OFF_RAW    12870656u           // 128*512 = 65536
#define OFF_MEAN   12936192u           // 512
#define OFF_XT     12936704u           // bf16 [C][M]: 12845056 ushorts = 6422528 floats
#define OFF_AT     19359232u           // bf16 [N][M]: 6422528 floats
// total = 25781760 floats = 103.1 MB

// d_out layout (float offsets)
#define OUT_CAT  0u        // 128*1024
#define OUT_WSUM 131072u   // 512*512
#define OUT_WNUM 393216u   // 512

using bf16x8 = __attribute__((ext_vector_type(8))) short;
using f32x4  = __attribute__((ext_vector_type(4))) float;

__device__ __forceinline__ unsigned short f2b(float f) {
    union { float f; unsigned u; } x; x.f = f;
    unsigned r = x.u + 0x7fffu + ((x.u >> 16) & 1u);   // RNE
    return (unsigned short)(r >> 16);
}

// ---------------- wnorm: ||w_n||^2 ----------------
__global__ __launch_bounds__(64) void k_wnorm(const float* __restrict__ w,
                                              float* __restrict__ wn) {
    int n = blockIdx.x, l = threadIdx.x;
    const float* p = w + (size_t)n * Cn + l * 8;
    float4 a = *(const float4*)p;
    float4 b = *(const float4*)(p + 4);
    float s = a.x*a.x + a.y*a.y + a.z*a.z + a.w*a.w
            + b.x*b.x + b.y*b.y + b.z*b.z + b.w*b.w;
    #pragma unroll
    for (int o = 32; o > 0; o >>= 1) s += __shfl_down(s, o);
    if (l == 0) wn[n] = s;
}

// ---------------- xnorm: ||x_row||^2 ----------------
__global__ __launch_bounds__(256) void k_xnorm(const float* __restrict__ fm,
                                               float* __restrict__ xn) {
    __shared__ float s[4][64];
    int t = threadIdx.x;
    int hq = t & 63, cg = t >> 6;
    int row = blockIdx.x * 64 + hq;             // < 25088 (392*64)
    int b = row / HWn, hw = row - b * HWn;
    const float* base = fm + (size_t)b * Cn * HWn + hw;
    float acc = 0.f;
    for (int c = cg; c < Cn; c += 4) {
        float v = base[(size_t)c * HWn];
        acc = fmaf(v, v, acc);
    }
    s[cg][hq] = acc;
    __syncthreads();
    if (cg == 0) xn[row] = s[0][hq] + s[1][hq] + s[2][hq] + s[3][hq];
}

// ---------------- prep: fm fp32 [b][c][hw] -> xt bf16 [c][b*196+hw] -------
__global__ __launch_bounds__(256) void k_prep(const float* __restrict__ fm,
                                              unsigned short* __restrict__ xt) {
    int b = blockIdx.x;
    int cg = blockIdx.y * 64;
    int t = threadIdx.x;
    // 64 c-rows x 49 float4 = 3136 float4 units
    for (int i = t; i < 64 * 49; i += 256) {
        int cl = i / 49, h4 = i - cl * 49;
        float4 v = *(const float4*)(fm + ((size_t)(b * Cn + cg + cl) * HWn) + h4 * 4);
        ushort4 o;
        o.x = f2b(v.x); o.y = f2b(v.y); o.z = f2b(v.z); o.w = f2b(v.w);
        *(ushort4*)(xt + (size_t)(cg + cl) * Mn + b * HWn + h4 * 4) = o;
    }
}

// ---------------- GEMM1: dot[m][n] = sum_k x[m][k]*w[n][k] ----------------
// tiles 64x64, BK=32, x[m][k] = fm[b, k, hw]  (fp32 VALU -- round-4 target)
__global__ __launch_bounds__(256) void k_dot(const float* __restrict__ fm,
                                             const float* __restrict__ w,
                                             float* __restrict__ dot) {
    __shared__ float As[32 * 68];   // [k][bm]
    __shared__ float Ws[32 * 68];   // [k][n]
    const int tid = threadIdx.x;
    const int bm0 = blockIdx.x * 64;
    const int n0  = blockIdx.y * 64;
    const int tm = tid & 15, tn = tid >> 4;
    const int bmq  = tid & 15;
    const int krow = tid >> 4;      // 0..15, also +16
    const int rowA = bm0 + 4 * bmq;
    const int bA   = rowA / HWn;
    const int hwA  = rowA - bA * HWn;
    const float* fmA = fm + (size_t)bA * Cn * HWn + hwA;
    const int kq   = tid & 7;       // 0..7
    const int nrow = tid >> 3;      // 0..31, also +32
    float acc[4][4] = {};
    for (int k0 = 0; k0 < Cn; k0 += 32) {
        float4 a0 = *(const float4*)(fmA + (size_t)(k0 + krow)      * HWn);
        float4 a1 = *(const float4*)(fmA + (size_t)(k0 + krow + 16) * HWn);
        float4 w0 = *(const float4*)(w + (size_t)(n0 + nrow)      * Cn + k0 + 4 * kq);
        float4 w1 = *(const float4*)(w + (size_t)(n0 + nrow + 32) * Cn + k0 + 4 * kq);
        __syncthreads();
        *(float4*)(As + krow        * 68 + 4 * bmq) = a0;
        *(float4*)(As + (krow + 16) * 68 + 4 * bmq) = a1;
        Ws[(4*kq+0)*68 + nrow] = w0.x;
        Ws[(4*kq+1)*68 + nrow] = w0.y;
        Ws[(4*kq+2)*68 + nrow] = w0.z;
        Ws[(4*kq+3)*68 + nrow] = w0.w;
        Ws[(4*kq+0)*68 + nrow + 32] = w1.x;
        Ws[(4*kq+1)*68 + nrow + 32] = w1.y;
        Ws[(4*kq+2)*68 + nrow + 32] = w1.z;
        Ws[(4*kq+3)*68 + nrow + 32] = w1.w;
        __syncthreads();
        #pragma unroll
        for (int k = 0; k < 32; ++k) {
            float4 a  = *(const float4*)(As + k * 68 + 4 * tm);
            float4 bv = *(const float4*)(Ws + k * 68 + 4 * tn);
            float av[4] = {a.x, a.y, a.z, a.w};
            float bw[4] = {bv.x, bv.y, bv.z, bv.w};
            #pragma unroll
            for (int i = 0; i < 4; ++i)
                #pragma unroll
                for (int j = 0; j < 4; ++j)
                    acc[i][j] = fmaf(av[i], bw[j], acc[i][j]);
        }
    }
    #pragma unroll
    for (int i = 0; i < 4; ++i) {
        float4 o = make_float4(acc[i][0], acc[i][1], acc[i][2], acc[i][3]);
        *(float4*)(dot + (size_t)(bm0 + 4 * tm + i) * Pn + n0 + 4 * tn) = o;
    }
}

// ---------------- reductions for softmax ----------------
__device__ __forceinline__ float blockMin(float v, float* red4) {
    #pragma unroll
    for (int o = 32; o > 0; o >>= 1) v = fminf(v, __shfl_down(v, o));
    int wid = threadIdx.x >> 6;
    if ((threadIdx.x & 63) == 0) red4[wid] = v;
    __syncthreads();
    float r = fminf(fminf(red4[0], red4[1]), fminf(red4[2], red4[3]));
    __syncthreads();
    return r;
}
__device__ __forceinline__ float blockSum(float v, float* red4) {
    #pragma unroll
    for (int o = 32; o > 0; o >>= 1) v += __shfl_down(v, o);
    int wid = threadIdx.x >> 6;
    if ((threadIdx.x & 63) == 0) red4[wid] = v;
    __syncthreads();
    float r = red4[0] + red4[1] + red4[2] + red4[3];
    __syncthreads();
    return r;
}

// ---------------- softmax + threshold (in place over dot buffer) ----------
__global__ __launch_bounds__(256) void k_softmax(float* __restrict__ da,
                                                 const float* __restrict__ xnorm,
                                                 const float* __restrict__ wnorm) {
    __shared__ float red4[4];
    const float invP = 1.0f / 512.0f;
    int t = threadIdx.x;
    int bm0 = blockIdx.x * 4;
    float wn0 = wnorm[t], wn1 = wnorm[t + 256];
    float d[4][2];
    #pragma unroll
    for (int r = 0; r < 4; ++r) {
        float xnv = xnorm[bm0 + r];
        size_t base = (size_t)(bm0 + r) * Pn;
        d[r][0] = xnv + wn0 - 2.0f * da[base + t];
        d[r][1] = xnv + wn1 - 2.0f * da[base + t + 256];
    }
    #pragma unroll
    for (int r = 0; r < 4; ++r) {
        float dmin = blockMin(fminf(d[r][0], d[r][1]), red4);
        float e0 = __expf(dmin - d[r][0]);
        float e1 = __expf(dmin - d[r][1]);
        float S = blockSum(e0 + e1, red4);
        float inv = 1.0f / S;
        float a0 = e0 * inv, a1 = e1 * inv;
        if (a0 < invP) a0 = 0.0f;
        if (a1 < invP) a1 = 0.0f;
        size_t base = (size_t)(bm0 + r) * Pn;
        da[base + t] = a0;
        da[base + t + 256] = a1;
    }
}

// ---------------- transpose: assign fp32 [M][N] -> at bf16 [N][M] ---------
__global__ __launch_bounds__(256) void k_tr(const float* __restrict__ assign,
                                            unsigned short* __restrict__ at) {
    __shared__ unsigned short tile[64][65];
    int m0 = blockIdx.x * 64, n0 = blockIdx.y * 64;
    int t = threadIdx.x;
    int mr = t >> 2, n4 = (t & 3) * 16;
    const float* src = assign + (size_t)(m0 + mr) * Pn + n0 + n4;
    #pragma unroll
    for (int q = 0; q < 4; ++q) {
        float4 v = *(const float4*)(src + q * 4);
        tile[mr][n4 + q*4 + 0] = f2b(v.x);
        tile[mr][n4 + q*4 + 1] = f2b(v.y);
        tile[mr][n4 + q*4 + 2] = f2b(v.z);
        tile[mr][n4 + q*4 + 3] = f2b(v.w);
    }
    __syncthreads();
    int nr = t >> 2, m4 = (t & 3) * 16;
    unsigned short o[16];
    #pragma unroll
    for (int j = 0; j < 16; ++j) o[j] = tile[m4 + j][nr];
    unsigned short* dst = at + (size_t)(n0 + nr) * Mn + m0 + m4;
    // 16 ushorts = 32 bytes -> TWO 16-byte stores (round-2 bug: only one)
    *(ulonglong2*)dst        = ((const ulonglong2*)o)[0];
    *(ulonglong2*)(dst + 8)  = ((const ulonglong2*)o)[1];
}

// ---------------- raw[b][p] = sum_m assign[b,m,p] ----------------
__global__ __launch_bounds__(128) void k_asum(const float* __restrict__ assign,
                                              float* __restrict__ raw) {
    int b = blockIdx.x;
    int n = blockIdx.y * 128 + threadIdx.x;
    const float* p = assign + (size_t)b * HWn * Pn + n;
    float s = 0.f;
    for (int m = 0; m < HWn; ++m) s += p[(size_t)m * Pn];
    raw[b * Pn + n] = s;
}

// ---------------- assign_mean + new_w_ep_num ----------------
__global__ __launch_bounds__(256) void k_reduce(const float* __restrict__ raw,
                                                const float* __restrict__ wnum,
                                                float* __restrict__ mean,
                                                float* __restrict__ outnum) {
    int n = blockIdx.x * 256 + threadIdx.x;
    float s = 0.f;
    for (int b = 0; b < Bn; ++b) s += raw[(size_t)b * Pn + n];
    mean[n] = s;
    outnum[n] = wnum[n] + (s > 1.0f ? s : 0.0f);
}

// ---------------- cvec + concat ----------------
__global__ __launch_bounds__(256) void k_cvec(const float* __restrict__ raw,
                                              const float* __restrict__ w,
                                              const float* __restrict__ emb,
                                              const int* __restrict__ epoch,
                                              float* __restrict__ out) {
    __shared__ float srow[512];
    int b = blockIdx.x, t = threadIdx.x;
    srow[t]       = raw[(size_t)b * Pn + t];
    srow[t + 256] = raw[(size_t)b * Pn + t + 256];
    __syncthreads();
    float a0 = 0.f, a1 = 0.f;
    for (int p = 0; p < Pn; ++p) {
        float ap = srow[p];
        a0 = fmaf(ap, w[(size_t)p * Cn + t], a0);
        a1 = fmaf(ap, w[(size_t)p * Cn + t + 256], a1);
    }
    const float sc = 1.0f / (196.0f * 512.0f);
    int ep = epoch[0];
    float c0 = (ep > 2) ? fmaxf(a0, 0.f) * sc : 0.f;
    float c1 = (ep > 2) ? fmaxf(a1, 0.f) * sc : 0.f;
    out[(size_t)b * 1024 + t]             = emb[(size_t)b * Cn + t];
    out[(size_t)b * 1024 + t + 256]       = emb[(size_t)b * Cn + t + 256];
    out[(size_t)b * 1024 + 512 + t]       = c0;
    out[(size_t)b * 1024 + 512 + t + 256] = c1;
}

// ---------------- GEMM2 (MFMA): update_w[n][c] = sum_m at[n][m]*xt[c][m] --
// block = 128(n) x 128(c), 4 waves (2x2 of 64x64), split-K chunks of 512 m
__global__ __launch_bounds__(256) void k_upw_mfma(const unsigned short* __restrict__ at,
                                                  const unsigned short* __restrict__ xt,
                                                  float* __restrict__ part) {
    int tid = threadIdx.x;
    int wave = tid >> 6, lane = tid & 63;
    int wn = wave >> 1, wc = wave & 1;
    int n0 = blockIdx.x * 128 + wn * 64;
    int c0 = blockIdx.y * 128 + wc * 64;
    int sp = blockIdx.z;
    int mbase = sp * 512 + (lane >> 4) * 8;
    int rl = lane & 15;
    const unsigned short* ap[4];
    const unsigned short* bp[4];
    #pragma unroll
    for (int f = 0; f < 4; ++f) {
        ap[f] = at + (size_t)(n0 + f * 16 + rl) * Mn + mbase;
        bp[f] = xt + (size_t)(c0 + f * 16 + rl) * Mn + mbase;
    }
    f32x4 acc[4][4] = {};
    for (int ks = 0; ks < 16; ++ks) {
        bf16x8 a[4], b[4];
        #pragma unroll
        for (int f = 0; f < 4; ++f) {
            a[f] = *(const bf16x8*)(ap[f] + ks * 32);
            b[f] = *(const bf16x8*)(bp[f] + ks * 32);
        }
        #pragma unroll
        for (int i = 0; i < 4; ++i)
            #pragma unroll
            for (int j = 0; j < 4; ++j)
                acc[i][j] = __builtin_amdgcn_mfma_f32_16x16x32_bf16(a[i], b[j], acc[i][j], 0, 0, 0);
    }
    float* o = part + (size_t)sp * (Pn * Cn);
    int rq = (lane >> 4) * 4;
    #pragma unroll
    for (int i = 0; i < 4; ++i) {
        #pragma unroll
        for (int j = 0; j < 4; ++j) {
            int n = n0 + i * 16 + rq;
            int c = c0 + j * 16 + rl;
            #pragma unroll
            for (int r = 0; r < 4; ++r)
                o[(size_t)(n + r) * Cn + c] = acc[i][j][r];
        }
    }
}

// ---------------- epilogue: new_w_ep_sum ----------------
__global__ __launch_bounds__(256) void k_wep(const float* __restrict__ part,
                                             const float* __restrict__ mean,
                                             const float* __restrict__ wsum,
                                             float* __restrict__ out1) {
    int n = blockIdx.x, t = threadIdx.x;
    bool upd = mean[n] > 1.0f;
    #pragma unroll
    for (int cc = 0; cc < 2; ++cc) {
        int c = t + cc * 256;
        float s = 0.f;
        for (int k = 0; k < SPLITK; ++k)
            s += part[(size_t)k * (Pn * Cn) + (size_t)n * Cn + c];
        size_t idx = (size_t)n * Cn + c;
        out1[idx] = wsum[idx] + (upd ? s : 0.f);
    }
}

extern "C" void kernel_launch(void* const* d_in, const int* in_sizes, int n_in,
                              void* d_out, int out_size, void* d_ws, size_t ws_size,
                              hipStream_t stream) {
    const float* fm    = (const float*)d_in[0];
    const float* emb   = (const float*)d_in[1];
    const float* w     = (const float*)d_in[2];
    const float* wsum  = (const float*)d_in[3];
    const float* wnum  = (const float*)d_in[4];
    const int*   epoch = (const int*)d_in[5];
    float* out = (float*)d_out;
    float* wsf = (float*)d_ws;

    float*          assignb = wsf + OFF_ASSIGN;
    float*          partb   = wsf + OFF_PART;      // alias of assignb (used after tr/asum)
    float*          xnormb  = wsf + OFF_XNORM;
    float*          wnormb  = wsf + OFF_WNORM;
    float*          rawb    = wsf + OFF_RAW;
    float*          meanb   = wsf + OFF_MEAN;
    unsigned short* xtb     = (unsigned short*)(wsf + OFF_XT);
    unsigned short* atb     = (unsigned short*)(wsf + OFF_AT);

    k_wnorm<<<512, 64, 0, stream>>>(w, wnormb);
    k_xnorm<<<392, 256, 0, stream>>>(fm, xnormb);
    k_prep<<<dim3(Bn, 8), 256, 0, stream>>>(fm, xtb);
    k_dot<<<dim3(Mn / 64, Pn / 64), 256, 0, stream>>>(fm, w, assignb);
    k_softmax<<<Mn / 4, 256, 0, stream>>>(assignb, xnormb, wnormb);
    k_tr<<<dim3(Mn / 64, Pn / 64), 256, 0, stream>>>(assignb, atb);
    k_asum<<<dim3(Bn, 4), 128, 0, stream>>>(assignb, rawb);
    k_reduce<<<2, 256, 0, stream>>>(rawb, wnum, meanb, out + OUT_WNUM);
    k_cvec<<<Bn, 256, 0, stream>>>(rawb, w, emb, epoch, out + OUT_CAT);
    k_upw_mfma<<<dim3(4, 4, SPLITK), 256, 0, stream>>>(atb, xtb, partb);
    k_wep<<<Pn, 256, 0, stream>>>(partb, meanb, wsum, out + OUT_WSUM);
}

// Round 4
// 244.822 us; speedup vs baseline: 2.1431x; 1.5576x over previous
//
#include <hip/hip_runtime.h>
#include <hip/hip_bf16.h>

// Problem constants
// B=128, C=512, H=W=14 -> HW=196, M=B*HW=25088, P=512
#define Bn   128
#define Cn   512
#define HWn  196
#define Mn   25088
#define Pn   512
#define SPLITK 49          // GEMM2 split-K chunks of 512 m each

// ws layout (float offsets)
#define OFF_ASSIGN 0u                  // 25088*512 fp32 (aliased by PART)
#define OFF_PART   0u                  // 49*512*512 fp32 (used after tr/asum done)
#define OFF_WNORM  12845056u           // 512
#define OFF_RAW    12845568u           // 128*512
#define OFF_MEAN   12911104u           // 512
#define OFF_XT     12911616u           // bf16 [C][M] (GEMM2 B): 6422528 floats
#define OFF_AT     19334144u           // bf16 [N][M] (GEMM2 A) / fp16 xm [M][C] (GEMM1 A) alias
#define OFF_WF     25756672u           // fp16 [N][C] (GEMM1 B): 131072 floats
// total = 25887744 floats = 103.6 MB

// d_out layout (float offsets)
#define OUT_CAT  0u        // 128*1024
#define OUT_WSUM 131072u   // 512*512
#define OUT_WNUM 393216u   // 512

using bf16x8 = __attribute__((ext_vector_type(8))) short;
using f16x8  = __attribute__((ext_vector_type(8))) _Float16;
using f32x4  = __attribute__((ext_vector_type(4))) float;

__device__ __forceinline__ unsigned short f2b(float f) {
    union { float f; unsigned u; } x; x.f = f;
    unsigned r = x.u + 0x7fffu + ((x.u >> 16) & 1u);   // RNE
    return (unsigned short)(r >> 16);
}

// ---------------- wnorm: ||w_n||^2  + w -> fp16 [N][C] ----------------
__global__ __launch_bounds__(64) void k_wnorm(const float* __restrict__ w,
                                              float* __restrict__ wn,
                                              _Float16* __restrict__ wf) {
    int n = blockIdx.x, l = threadIdx.x;
    const float* p = w + (size_t)n * Cn + l * 8;
    float4 a = *(const float4*)p;
    float4 b = *(const float4*)(p + 4);
    float s = a.x*a.x + a.y*a.y + a.z*a.z + a.w*a.w
            + b.x*b.x + b.y*b.y + b.z*b.z + b.w*b.w;
    alignas(16) _Float16 h[8];
    h[0]=(_Float16)a.x; h[1]=(_Float16)a.y; h[2]=(_Float16)a.z; h[3]=(_Float16)a.w;
    h[4]=(_Float16)b.x; h[5]=(_Float16)b.y; h[6]=(_Float16)b.z; h[7]=(_Float16)b.w;
    *(float4*)(wf + (size_t)n * Cn + l * 8) = *(const float4*)h;
    #pragma unroll
    for (int o = 32; o > 0; o >>= 1) s += __shfl_down(s, o);
    if (l == 0) wn[n] = s;
}

// ---------------- prep: fm fp32 [b][c][hw] -> xm fp16 [b*196+hw][c] -------
__global__ __launch_bounds__(256) void k_prep_xm(const float* __restrict__ fm,
                                                 _Float16* __restrict__ xm) {
    __shared__ _Float16 tile[64][202];   // 101 dwords/row, odd -> conflict-light
    int b = blockIdx.x;
    int cg = blockIdx.y * 64;
    int t = threadIdx.x;
    for (int i = t; i < 64 * 49; i += 256) {
        int cl = i / 49, h4 = i - cl * 49;
        float4 v = *(const float4*)(fm + ((size_t)(b * Cn + cg + cl) * HWn) + h4 * 4);
        tile[cl][h4*4+0] = (_Float16)v.x;
        tile[cl][h4*4+1] = (_Float16)v.y;
        tile[cl][h4*4+2] = (_Float16)v.z;
        tile[cl][h4*4+3] = (_Float16)v.w;
    }
    __syncthreads();
    for (int i = t; i < HWn * 8; i += 256) {
        int row = i >> 3, seg = i & 7;
        alignas(16) _Float16 h[8];
        #pragma unroll
        for (int j = 0; j < 8; ++j) h[j] = tile[seg * 8 + j][row];
        *(float4*)(xm + (size_t)(b * HWn + row) * Cn + cg + seg * 8) = *(const float4*)h;
    }
}

// ---------------- prep: fm fp32 [b][c][hw] -> xt bf16 [c][b*196+hw] -------
__global__ __launch_bounds__(256) void k_prep(const float* __restrict__ fm,
                                              unsigned short* __restrict__ xt) {
    int b = blockIdx.x;
    int cg = blockIdx.y * 64;
    int t = threadIdx.x;
    for (int i = t; i < 64 * 49; i += 256) {
        int cl = i / 49, h4 = i - cl * 49;
        float4 v = *(const float4*)(fm + ((size_t)(b * Cn + cg + cl) * HWn) + h4 * 4);
        ushort4 o;
        o.x = f2b(v.x); o.y = f2b(v.y); o.z = f2b(v.z); o.w = f2b(v.w);
        *(ushort4*)(xt + (size_t)(cg + cl) * Mn + b * HWn + h4 * 4) = o;
    }
}

// ---------------- GEMM1 (MFMA fp16): dot[m][n] = sum_k xm[m][k]*wf[n][k] --
// block = 128(m) x 128(n), 4 waves 2x2 of 64x64, direct-global fragments
__global__ __launch_bounds__(256) void k_dot_mfma(const _Float16* __restrict__ xm,
                                                  const _Float16* __restrict__ wf,
                                                  float* __restrict__ dot) {
    int tid = threadIdx.x;
    int wave = tid >> 6, lane = tid & 63;
    int wm = wave >> 1, wnn = wave & 1;
    int m0 = blockIdx.x * 128 + wm * 64;
    int n0 = blockIdx.y * 128 + wnn * 64;
    int rl = lane & 15;
    int kb = (lane >> 4) * 8;
    const _Float16* ap[4];
    const _Float16* bp[4];
    #pragma unroll
    for (int f = 0; f < 4; ++f) {
        ap[f] = xm + (size_t)(m0 + f * 16 + rl) * Cn + kb;
        bp[f] = wf + (size_t)(n0 + f * 16 + rl) * Cn + kb;
    }
    f32x4 acc[4][4] = {};
    for (int ks = 0; ks < 16; ++ks) {
        f16x8 a[4], b[4];
        #pragma unroll
        for (int f = 0; f < 4; ++f) {
            a[f] = *(const f16x8*)(ap[f] + ks * 32);
            b[f] = *(const f16x8*)(bp[f] + ks * 32);
        }
        #pragma unroll
        for (int i = 0; i < 4; ++i)
            #pragma unroll
            for (int j = 0; j < 4; ++j)
                acc[i][j] = __builtin_amdgcn_mfma_f32_16x16x32_f16(a[i], b[j], acc[i][j], 0, 0, 0);
    }
    int rq = (lane >> 4) * 4;
    #pragma unroll
    for (int i = 0; i < 4; ++i)
        #pragma unroll
        for (int j = 0; j < 4; ++j)
            #pragma unroll
            for (int r = 0; r < 4; ++r)
                dot[(size_t)(m0 + i * 16 + rq + r) * Pn + n0 + j * 16 + rl] = acc[i][j][r];
}

// ---------------- reductions for softmax ----------------
__device__ __forceinline__ float blockMax(float v, float* red4) {
    #pragma unroll
    for (int o = 32; o > 0; o >>= 1) v = fmaxf(v, __shfl_down(v, o));
    int wid = threadIdx.x >> 6;
    if ((threadIdx.x & 63) == 0) red4[wid] = v;
    __syncthreads();
    float r = fmaxf(fmaxf(red4[0], red4[1]), fmaxf(red4[2], red4[3]));
    __syncthreads();
    return r;
}
__device__ __forceinline__ float blockSum(float v, float* red4) {
    #pragma unroll
    for (int o = 32; o > 0; o >>= 1) v += __shfl_down(v, o);
    int wid = threadIdx.x >> 6;
    if ((threadIdx.x & 63) == 0) red4[wid] = v;
    __syncthreads();
    float r = red4[0] + red4[1] + red4[2] + red4[3];
    __syncthreads();
    return r;
}

// ------- softmax + threshold, score = 2*dot - ||w||^2 (xnorm cancels) -----
__global__ __launch_bounds__(256) void k_softmax(float* __restrict__ da,
                                                 const float* __restrict__ wnorm) {
    __shared__ float red4[4];
    const float invP = 1.0f / 512.0f;
    int t = threadIdx.x;
    int bm0 = blockIdx.x * 4;
    float wn0 = wnorm[t], wn1 = wnorm[t + 256];
    float s[4][2];
    #pragma unroll
    for (int r = 0; r < 4; ++r) {
        size_t base = (size_t)(bm0 + r) * Pn;
        s[r][0] = 2.0f * da[base + t]       - wn0;
        s[r][1] = 2.0f * da[base + t + 256] - wn1;
    }
    #pragma unroll
    for (int r = 0; r < 4; ++r) {
        float smax = blockMax(fmaxf(s[r][0], s[r][1]), red4);
        float e0 = __expf(s[r][0] - smax);
        float e1 = __expf(s[r][1] - smax);
        float S = blockSum(e0 + e1, red4);
        float inv = 1.0f / S;
        float a0 = e0 * inv, a1 = e1 * inv;
        if (a0 < invP) a0 = 0.0f;
        if (a1 < invP) a1 = 0.0f;
        size_t base = (size_t)(bm0 + r) * Pn;
        da[base + t] = a0;
        da[base + t + 256] = a1;
    }
}

// ---------------- transpose: assign fp32 [M][N] -> at bf16 [N][M] ---------
__global__ __launch_bounds__(256) void k_tr(const float* __restrict__ assign,
                                            unsigned short* __restrict__ at) {
    __shared__ unsigned short tile[64][65];
    int m0 = blockIdx.x * 64, n0 = blockIdx.y * 64;
    int t = threadIdx.x;
    int mr = t >> 2, n4 = (t & 3) * 16;
    const float* src = assign + (size_t)(m0 + mr) * Pn + n0 + n4;
    #pragma unroll
    for (int q = 0; q < 4; ++q) {
        float4 v = *(const float4*)(src + q * 4);
        tile[mr][n4 + q*4 + 0] = f2b(v.x);
        tile[mr][n4 + q*4 + 1] = f2b(v.y);
        tile[mr][n4 + q*4 + 2] = f2b(v.z);
        tile[mr][n4 + q*4 + 3] = f2b(v.w);
    }
    __syncthreads();
    int nr = t >> 2, m4 = (t & 3) * 16;
    unsigned short o[16];
    #pragma unroll
    for (int j = 0; j < 16; ++j) o[j] = tile[m4 + j][nr];
    unsigned short* dst = at + (size_t)(n0 + nr) * Mn + m0 + m4;
    *(ulonglong2*)dst        = ((const ulonglong2*)o)[0];
    *(ulonglong2*)(dst + 8)  = ((const ulonglong2*)o)[1];
}

// ---------------- raw[b][p] = sum_m assign[b,m,p] ----------------
__global__ __launch_bounds__(128) void k_asum(const float* __restrict__ assign,
                                              float* __restrict__ raw) {
    int b = blockIdx.x;
    int n = blockIdx.y * 128 + threadIdx.x;
    const float* p = assign + (size_t)b * HWn * Pn + n;
    float s = 0.f;
    for (int m = 0; m < HWn; ++m) s += p[(size_t)m * Pn];
    raw[b * Pn + n] = s;
}

// ---------------- assign_mean + new_w_ep_num ----------------
__global__ __launch_bounds__(256) void k_reduce(const float* __restrict__ raw,
                                                const float* __restrict__ wnum,
                                                float* __restrict__ mean,
                                                float* __restrict__ outnum) {
    int n = blockIdx.x * 256 + threadIdx.x;
    float s = 0.f;
    for (int b = 0; b < Bn; ++b) s += raw[(size_t)b * Pn + n];
    mean[n] = s;
    outnum[n] = wnum[n] + (s > 1.0f ? s : 0.0f);
}

// ---------------- cvec + concat ----------------
__global__ __launch_bounds__(256) void k_cvec(const float* __restrict__ raw,
                                              const float* __restrict__ w,
                                              const float* __restrict__ emb,
                                              const int* __restrict__ epoch,
                                              float* __restrict__ out) {
    __shared__ float srow[512];
    int b = blockIdx.x, t = threadIdx.x;
    srow[t]       = raw[(size_t)b * Pn + t];
    srow[t + 256] = raw[(size_t)b * Pn + t + 256];
    __syncthreads();
    float a0 = 0.f, a1 = 0.f;
    for (int p = 0; p < Pn; ++p) {
        float ap = srow[p];
        a0 = fmaf(ap, w[(size_t)p * Cn + t], a0);
        a1 = fmaf(ap, w[(size_t)p * Cn + t + 256], a1);
    }
    const float sc = 1.0f / (196.0f * 512.0f);
    int ep = epoch[0];
    float c0 = (ep > 2) ? fmaxf(a0, 0.f) * sc : 0.f;
    float c1 = (ep > 2) ? fmaxf(a1, 0.f) * sc : 0.f;
    out[(size_t)b * 1024 + t]             = emb[(size_t)b * Cn + t];
    out[(size_t)b * 1024 + t + 256]       = emb[(size_t)b * Cn + t + 256];
    out[(size_t)b * 1024 + 512 + t]       = c0;
    out[(size_t)b * 1024 + 512 + t + 256] = c1;
}

// ---------------- GEMM2 (MFMA): update_w[n][c] = sum_m at[n][m]*xt[c][m] --
__global__ __launch_bounds__(256) void k_upw_mfma(const unsigned short* __restrict__ at,
                                                  const unsigned short* __restrict__ xt,
                                                  float* __restrict__ part) {
    int tid = threadIdx.x;
    int wave = tid >> 6, lane = tid & 63;
    int wn = wave >> 1, wc = wave & 1;
    int n0 = blockIdx.x * 128 + wn * 64;
    int c0 = blockIdx.y * 128 + wc * 64;
    int sp = blockIdx.z;
    int mbase = sp * 512 + (lane >> 4) * 8;
    int rl = lane & 15;
    const unsigned short* ap[4];
    const unsigned short* bp[4];
    #pragma unroll
    for (int f = 0; f < 4; ++f) {
        ap[f] = at + (size_t)(n0 + f * 16 + rl) * Mn + mbase;
        bp[f] = xt + (size_t)(c0 + f * 16 + rl) * Mn + mbase;
    }
    f32x4 acc[4][4] = {};
    for (int ks = 0; ks < 16; ++ks) {
        bf16x8 a[4], b[4];
        #pragma unroll
        for (int f = 0; f < 4; ++f) {
            a[f] = *(const bf16x8*)(ap[f] + ks * 32);
            b[f] = *(const bf16x8*)(bp[f] + ks * 32);
        }
        #pragma unroll
        for (int i = 0; i < 4; ++i)
            #pragma unroll
            for (int j = 0; j < 4; ++j)
                acc[i][j] = __builtin_amdgcn_mfma_f32_16x16x32_bf16(a[i], b[j], acc[i][j], 0, 0, 0);
    }
    float* o = part + (size_t)sp * (Pn * Cn);
    int rq = (lane >> 4) * 4;
    #pragma unroll
    for (int i = 0; i < 4; ++i) {
        #pragma unroll
        for (int j = 0; j < 4; ++j) {
            int n = n0 + i * 16 + rq;
            int c = c0 + j * 16 + rl;
            #pragma unroll
            for (int r = 0; r < 4; ++r)
                o[(size_t)(n + r) * Cn + c] = acc[i][j][r];
        }
    }
}

// ---------------- epilogue: new_w_ep_sum ----------------
__global__ __launch_bounds__(256) void k_wep(const float* __restrict__ part,
                                             const float* __restrict__ mean,
                                             const float* __restrict__ wsum,
                                             float* __restrict__ out1) {
    int n = blockIdx.x, t = threadIdx.x;
    bool upd = mean[n] > 1.0f;
    #pragma unroll
    for (int cc = 0; cc < 2; ++cc) {
        int c = t + cc * 256;
        float s = 0.f;
        for (int k = 0; k < SPLITK; ++k)
            s += part[(size_t)k * (Pn * Cn) + (size_t)n * Cn + c];
        size_t idx = (size_t)n * Cn + c;
        out1[idx] = wsum[idx] + (upd ? s : 0.f);
    }
}

extern "C" void kernel_launch(void* const* d_in, const int* in_sizes, int n_in,
                              void* d_out, int out_size, void* d_ws, size_t ws_size,
                              hipStream_t stream) {
    const float* fm    = (const float*)d_in[0];
    const float* emb   = (const float*)d_in[1];
    const float* w     = (const float*)d_in[2];
    const float* wsum  = (const float*)d_in[3];
    const float* wnum  = (const float*)d_in[4];
    const int*   epoch = (const int*)d_in[5];
    float* out = (float*)d_out;
    float* wsf = (float*)d_ws;

    float*          assignb = wsf + OFF_ASSIGN;
    float*          partb   = wsf + OFF_PART;      // alias of assignb
    float*          wnormb  = wsf + OFF_WNORM;
    float*          rawb    = wsf + OFF_RAW;
    float*          meanb   = wsf + OFF_MEAN;
    unsigned short* xtb     = (unsigned short*)(wsf + OFF_XT);
    unsigned short* atb     = (unsigned short*)(wsf + OFF_AT);
    _Float16*       xmb     = (_Float16*)(wsf + OFF_AT);   // alias: xm dead before at written
    _Float16*       wfb     = (_Float16*)(wsf + OFF_WF);

    k_wnorm<<<512, 64, 0, stream>>>(w, wnormb, wfb);
    k_prep_xm<<<dim3(Bn, 8), 256, 0, stream>>>(fm, xmb);
    k_prep<<<dim3(Bn, 8), 256, 0, stream>>>(fm, xtb);
    k_dot_mfma<<<dim3(Mn / 128, Pn / 128), 256, 0, stream>>>(xmb, wfb, assignb);
    k_softmax<<<Mn / 4, 256, 0, stream>>>(assignb, wnormb);
    k_tr<<<dim3(Mn / 64, Pn / 64), 256, 0, stream>>>(assignb, atb);
    k_asum<<<dim3(Bn, 4), 128, 0, stream>>>(assignb, rawb);
    k_reduce<<<2, 256, 0, stream>>>(rawb, wnum, meanb, out + OUT_WNUM);
    k_cvec<<<Bn, 256, 0, stream>>>(rawb, w, emb, epoch, out + OUT_CAT);
    k_upw_mfma<<<dim3(4, 4, SPLITK), 256, 0, stream>>>(atb, xtb, partb);
    k_wep<<<Pn, 256, 0, stream>>>(partb, meanb, wsum, out + OUT_WSUM);
}

// Round 5
// 197.428 us; speedup vs baseline: 2.6575x; 1.2401x over previous
//
#include <hip/hip_runtime.h>
#include <hip/hip_bf16.h>

// Problem constants
// B=128, C=512, H=W=14 -> HW=196, M=B*HW=25088, P=512
#define Bn   128
#define Cn   512
#define HWn  196
#define Mn   25088
#define Pn   512
#define MPAD 32768         // padded m': b*256 + chunk*64 + j (chunk=hw/49, j=hw%49)
#define SPLITK2 16         // GEMM2 split-K chunks of 2048 m'
#define KCH  2048

// ws layout (float offsets)
#define OFF_XM     0u          // fp16 [25216][512] = 12,910,592 ush = 6,455,296 f
#define OFF_PART   0u          // 16*512*512 fp32 = 4,194,304 f (alias: xm dead before GEMM2)
#define OFF_XT     6455296u    // bf16 [512][32768] = 8,388,608 f
#define OFF_AT     14843904u   // bf16 [512][32768] = 8,388,608 f
#define OFF_WF     23232512u   // fp16 [512][512] = 131,072 f
#define OFF_WNORM  23363584u   // 512
#define OFF_RAWP   23364096u   // 256*512 = 131,072
#define OFF_MEAN   23495168u   // 512
// total = 23,495,680 floats = 94.0 MB

// d_out layout (float offsets)
#define OUT_CAT  0u        // 128*1024
#define OUT_WSUM 131072u   // 512*512
#define OUT_WNUM 393216u   // 512

using bf16x8 = __attribute__((ext_vector_type(8))) short;
using f16x8  = __attribute__((ext_vector_type(8))) _Float16;
using f32x4  = __attribute__((ext_vector_type(4))) float;

__device__ __forceinline__ unsigned short f2b(float f) {
    union { float f; unsigned u; } x; x.f = f;
    unsigned r = x.u + 0x7fffu + ((x.u >> 16) & 1u);   // RNE
    return (unsigned short)(r >> 16);
}

// ---------------- wnorm: ||w_n||^2  + w -> fp16 [N][C] ----------------
__global__ __launch_bounds__(64) void k_wnorm(const float* __restrict__ w,
                                              float* __restrict__ wn,
                                              _Float16* __restrict__ wf) {
    int n = blockIdx.x, l = threadIdx.x;
    const float* p = w + (size_t)n * Cn + l * 8;
    float4 a = *(const float4*)p;
    float4 b = *(const float4*)(p + 4);
    float s = a.x*a.x + a.y*a.y + a.z*a.z + a.w*a.w
            + b.x*b.x + b.y*b.y + b.z*b.z + b.w*b.w;
    alignas(16) _Float16 h[8];
    h[0]=(_Float16)a.x; h[1]=(_Float16)a.y; h[2]=(_Float16)a.z; h[3]=(_Float16)a.w;
    h[4]=(_Float16)b.x; h[5]=(_Float16)b.y; h[6]=(_Float16)b.z; h[7]=(_Float16)b.w;
    *(float4*)(wf + (size_t)n * Cn + l * 8) = *(const float4*)h;
    #pragma unroll
    for (int o = 32; o > 0; o >>= 1) s += __shfl_down(s, o);
    if (l == 0) wn[n] = s;
}

// ------- prep2: fm fp32 [b][c][hw] -> xm fp16 [m][c]  AND xt bf16 [c][m'] -
__global__ __launch_bounds__(512) void k_prep2(const float* __restrict__ fm,
                                               _Float16* __restrict__ xm,
                                               unsigned short* __restrict__ xt) {
    __shared__ _Float16 tile[64][200];
    int b = blockIdx.x;
    int cg = blockIdx.y * 64;
    int t = threadIdx.x;
    // load 64 c-rows x 196 hw (49 float4 each)
    for (int i = t; i < 64 * 49; i += 512) {
        int cl = i / 49, h4 = i - cl * 49;
        float4 v = *(const float4*)(fm + ((size_t)(b * Cn + cg + cl) * HWn) + h4 * 4);
        tile[cl][h4*4+0] = (_Float16)v.x;
        tile[cl][h4*4+1] = (_Float16)v.y;
        tile[cl][h4*4+2] = (_Float16)v.z;
        tile[cl][h4*4+3] = (_Float16)v.w;
    }
    __syncthreads();
    // xm: transposed fp16 [m][c]
    for (int i = t; i < HWn * 8; i += 512) {
        int hw = i >> 3, seg = i & 7;
        alignas(16) _Float16 h[8];
        #pragma unroll
        for (int j = 0; j < 8; ++j) h[j] = tile[seg * 8 + j][hw];
        *(float4*)(xm + (size_t)(b * HWn + hw) * Cn + cg + seg * 8) = *(const float4*)h;
    }
    // xt: bf16 [c][b*256 + q*64 + j], j<49 valid, 49..63 zero
    for (int i = t; i < 64 * 4 * 16; i += 512) {
        int cl = i >> 6, rem = i & 63;
        int q = rem >> 4, j4 = rem & 15;
        ushort4 o;
        if (j4 < 12) {
            o.x = f2b((float)tile[cl][q*49 + j4*4 + 0]);
            o.y = f2b((float)tile[cl][q*49 + j4*4 + 1]);
            o.z = f2b((float)tile[cl][q*49 + j4*4 + 2]);
            o.w = f2b((float)tile[cl][q*49 + j4*4 + 3]);
        } else if (j4 == 12) {
            o.x = f2b((float)tile[cl][q*49 + 48]);
            o.y = 0; o.z = 0; o.w = 0;
        } else {
            o.x = 0; o.y = 0; o.z = 0; o.w = 0;
        }
        *(ushort4*)(xt + (size_t)(cg + cl) * MPAD + b * 256 + q * 64 + j4 * 4) = o;
    }
}

// --- k_post: fused GEMM1(fp16 MFMA) + softmax + threshold + at + colsums --
// grid 256: block = (b, half) -> 98 rows x all 512 n. 8 waves (2 mq x 4 nq).
__global__ __launch_bounds__(512, 2) void k_post(const _Float16* __restrict__ xm,
                                                 const _Float16* __restrict__ wf,
                                                 const float* __restrict__ wnorm,
                                                 unsigned short* __restrict__ at,
                                                 float* __restrict__ rawp) {
    __shared__ _Float16 As[113][72];     // 144B row stride -> 2-way (free) on frag reads
    __shared__ float red[2][64][4];
    __shared__ float colp[2][512];
    const int bid = blockIdx.x;
    const int b = bid >> 1, half = bid & 1;
    const int tid = threadIdx.x;
    const int wave = tid >> 6, lane = tid & 63;
    const int mq = wave >> 2, nq = wave & 3;
    const int rl = lane & 15, rq = lane >> 4;
    const int kb = rq * 8;
    const int m0 = b * 196 + half * 98;
    const int n0 = nq * 128;
    const int srow = tid >> 2;
    const int sk16 = (tid & 3) * 8;

    const _Float16* bp[8];
    #pragma unroll
    for (int g = 0; g < 8; ++g)
        bp[g] = wf + (size_t)(n0 + g * 16 + rl) * Cn + kb;

    f32x4 acc[4][8] = {};
    for (int c = 0; c < 8; ++c) {
        const int k0 = c * 64;
        __syncthreads();
        if (srow < 113) {
            const _Float16* src = xm + (size_t)(m0 + srow) * Cn + k0 + sk16;
            f16x8 v0 = *(const f16x8*)src;
            f16x8 v1 = *(const f16x8*)(src + 32);
            *(f16x8*)&As[srow][sk16]      = v0;
            *(f16x8*)&As[srow][32 + sk16] = v1;
        }
        __syncthreads();
        #pragma unroll
        for (int ks = 0; ks < 2; ++ks) {
            f16x8 a[4], bb[8];
            #pragma unroll
            for (int f = 0; f < 4; ++f)
                a[f] = *(const f16x8*)&As[mq * 49 + f * 16 + rl][ks * 32 + kb];
            #pragma unroll
            for (int g = 0; g < 8; ++g)
                bb[g] = *(const f16x8*)(bp[g] + k0 + ks * 32);
            #pragma unroll
            for (int f = 0; f < 4; ++f)
                #pragma unroll
                for (int g = 0; g < 8; ++g)
                    acc[f][g] = __builtin_amdgcn_mfma_f32_16x16x32_f16(a[f], bb[g], acc[f][g], 0, 0, 0);
        }
    }
    // scores: 2*dot - ||w||^2
    float wn[8];
    #pragma unroll
    for (int g = 0; g < 8; ++g) wn[g] = wnorm[n0 + g * 16 + rl];
    #pragma unroll
    for (int f = 0; f < 4; ++f)
        #pragma unroll
        for (int g = 0; g < 8; ++g)
            #pragma unroll
            for (int r = 0; r < 4; ++r)
                acc[f][g][r] = 2.0f * acc[f][g][r] - wn[g];
    // row max across block
    float mx[4][4];
    #pragma unroll
    for (int f = 0; f < 4; ++f)
        #pragma unroll
        for (int r = 0; r < 4; ++r) {
            float m_ = acc[f][0][r];
            #pragma unroll
            for (int g = 1; g < 8; ++g) m_ = fmaxf(m_, acc[f][g][r]);
            #pragma unroll
            for (int o = 8; o >= 1; o >>= 1) m_ = fmaxf(m_, __shfl_xor(m_, o));
            mx[f][r] = m_;
        }
    if (rl == 0)
        #pragma unroll
        for (int f = 0; f < 4; ++f)
            #pragma unroll
            for (int r = 0; r < 4; ++r)
                red[mq][f * 16 + rq * 4 + r][nq] = mx[f][r];
    __syncthreads();
    float rmax[4][4];
    #pragma unroll
    for (int f = 0; f < 4; ++f)
        #pragma unroll
        for (int r = 0; r < 4; ++r) {
            float* q = red[mq][f * 16 + rq * 4 + r];
            rmax[f][r] = fmaxf(fmaxf(q[0], q[1]), fmaxf(q[2], q[3]));
        }
    // exp + row sums
    float sm[4][4];
    #pragma unroll
    for (int f = 0; f < 4; ++f)
        #pragma unroll
        for (int r = 0; r < 4; ++r) {
            float s_ = 0.f;
            #pragma unroll
            for (int g = 0; g < 8; ++g) {
                float p = __expf(acc[f][g][r] - rmax[f][r]);
                acc[f][g][r] = p;
                s_ += p;
            }
            #pragma unroll
            for (int o = 8; o >= 1; o >>= 1) s_ += __shfl_xor(s_, o);
            sm[f][r] = s_;
        }
    __syncthreads();
    if (rl == 0)
        #pragma unroll
        for (int f = 0; f < 4; ++f)
            #pragma unroll
            for (int r = 0; r < 4; ++r)
                red[mq][f * 16 + rq * 4 + r][nq] = sm[f][r];
    __syncthreads();
    const float invP = 1.0f / 512.0f;
    #pragma unroll
    for (int f = 0; f < 4; ++f)
        #pragma unroll
        for (int r = 0; r < 4; ++r) {
            float* q = red[mq][f * 16 + rq * 4 + r];
            float inv = 1.0f / (q[0] + q[1] + q[2] + q[3]);
            #pragma unroll
            for (int g = 0; g < 8; ++g) {
                float a = acc[f][g][r] * inv;
                acc[f][g][r] = (a < invP) ? 0.0f : a;
            }
        }
    // column sums over valid rows (mloc < 49)
    float cs[8] = {};
    #pragma unroll
    for (int g = 0; g < 8; ++g) {
        #pragma unroll
        for (int f = 0; f < 4; ++f)
            #pragma unroll
            for (int r = 0; r < 4; ++r)
                if (f * 16 + rq * 4 + r < 49) cs[g] += acc[f][g][r];
        cs[g] += __shfl_xor(cs[g], 16);
        cs[g] += __shfl_xor(cs[g], 32);
    }
    if (rq == 0)
        #pragma unroll
        for (int g = 0; g < 8; ++g) colp[mq][n0 + g * 16 + rl] = cs[g];
    __syncthreads();
    if (tid < 512) rawp[(size_t)bid * 512 + tid] = colp[0][tid] + colp[1][tid];
    // at write: bf16 [n][b*256 + chunk*64 + mloc], pad rows 49..63 = 0
    const int mb = b * 256 + (half * 2 + mq) * 64;
    #pragma unroll
    for (int f = 0; f < 4; ++f) {
        const int mloc = f * 16 + rq * 4;
        #pragma unroll
        for (int g = 0; g < 8; ++g) {
            ushort4 o;
            o.x = (mloc + 0 < 49) ? f2b(acc[f][g][0]) : (unsigned short)0;
            o.y = (mloc + 1 < 49) ? f2b(acc[f][g][1]) : (unsigned short)0;
            o.z = (mloc + 2 < 49) ? f2b(acc[f][g][2]) : (unsigned short)0;
            o.w = (mloc + 3 < 49) ? f2b(acc[f][g][3]) : (unsigned short)0;
            *(ushort4*)(at + (size_t)(n0 + g * 16 + rl) * MPAD + mb + mloc) = o;
        }
    }
}

// ---------------- assign_mean + new_w_ep_num ----------------
__global__ __launch_bounds__(256) void k_reduce(const float* __restrict__ rawp,
                                                const float* __restrict__ wnum,
                                                float* __restrict__ mean,
                                                float* __restrict__ outnum) {
    int n = blockIdx.x * 256 + threadIdx.x;
    float s = 0.f;
    for (int r = 0; r < 256; ++r) s += rawp[(size_t)r * Pn + n];
    mean[n] = s;
    outnum[n] = wnum[n] + (s > 1.0f ? s : 0.0f);
}

// ---------------- cvec + concat ----------------
__global__ __launch_bounds__(256) void k_cvec(const float* __restrict__ rawp,
                                              const float* __restrict__ w,
                                              const float* __restrict__ emb,
                                              const int* __restrict__ epoch,
                                              float* __restrict__ out) {
    __shared__ float srow[512];
    int b = blockIdx.x, t = threadIdx.x;
    srow[t]       = rawp[(size_t)(2*b) * Pn + t]       + rawp[(size_t)(2*b+1) * Pn + t];
    srow[t + 256] = rawp[(size_t)(2*b) * Pn + t + 256] + rawp[(size_t)(2*b+1) * Pn + t + 256];
    __syncthreads();
    float a0 = 0.f, a1 = 0.f;
    for (int p = 0; p < Pn; ++p) {
        float ap = srow[p];
        a0 = fmaf(ap, w[(size_t)p * Cn + t], a0);
        a1 = fmaf(ap, w[(size_t)p * Cn + t + 256], a1);
    }
    const float sc = 1.0f / (196.0f * 512.0f);
    int ep = epoch[0];
    float c0 = (ep > 2) ? fmaxf(a0, 0.f) * sc : 0.f;
    float c1 = (ep > 2) ? fmaxf(a1, 0.f) * sc : 0.f;
    out[(size_t)b * 1024 + t]             = emb[(size_t)b * Cn + t];
    out[(size_t)b * 1024 + t + 256]       = emb[(size_t)b * Cn + t + 256];
    out[(size_t)b * 1024 + 512 + t]       = c0;
    out[(size_t)b * 1024 + 512 + t + 256] = c1;
}

// ---------------- GEMM2 (MFMA): update_w[n][c] = sum_m' at[n][m']*xt[c][m']
__global__ __launch_bounds__(256) void k_upw_mfma(const unsigned short* __restrict__ at,
                                                  const unsigned short* __restrict__ xt,
                                                  float* __restrict__ part) {
    int tid = threadIdx.x;
    int wave = tid >> 6, lane = tid & 63;
    int wn = wave >> 1, wc = wave & 1;
    int n0 = blockIdx.x * 128 + wn * 64;
    int c0 = blockIdx.y * 128 + wc * 64;
    int sp = blockIdx.z;
    int mbase = sp * KCH + (lane >> 4) * 8;
    int rl = lane & 15;
    const unsigned short* ap[4];
    const unsigned short* bp[4];
    #pragma unroll
    for (int f = 0; f < 4; ++f) {
        ap[f] = at + (size_t)(n0 + f * 16 + rl) * MPAD + mbase;
        bp[f] = xt + (size_t)(c0 + f * 16 + rl) * MPAD + mbase;
    }
    f32x4 acc[4][4] = {};
    for (int ks = 0; ks < KCH / 32; ++ks) {
        bf16x8 a[4], b[4];
        #pragma unroll
        for (int f = 0; f < 4; ++f) {
            a[f] = *(const bf16x8*)(ap[f] + ks * 32);
            b[f] = *(const bf16x8*)(bp[f] + ks * 32);
        }
        #pragma unroll
        for (int i = 0; i < 4; ++i)
            #pragma unroll
            for (int j = 0; j < 4; ++j)
                acc[i][j] = __builtin_amdgcn_mfma_f32_16x16x32_bf16(a[i], b[j], acc[i][j], 0, 0, 0);
    }
    float* o = part + (size_t)sp * (Pn * Cn);
    int rq = (lane >> 4) * 4;
    #pragma unroll
    for (int i = 0; i < 4; ++i) {
        #pragma unroll
        for (int j = 0; j < 4; ++j) {
            int n = n0 + i * 16 + rq;
            int c = c0 + j * 16 + rl;
            #pragma unroll
            for (int r = 0; r < 4; ++r)
                o[(size_t)(n + r) * Cn + c] = acc[i][j][r];
        }
    }
}

// ---------------- epilogue: new_w_ep_sum ----------------
__global__ __launch_bounds__(256) void k_wep(const float* __restrict__ part,
                                             const float* __restrict__ mean,
                                             const float* __restrict__ wsum,
                                             float* __restrict__ out1) {
    int n = blockIdx.x, t = threadIdx.x;
    bool upd = mean[n] > 1.0f;
    #pragma unroll
    for (int cc = 0; cc < 2; ++cc) {
        int c = t + cc * 256;
        float s = 0.f;
        #pragma unroll
        for (int k = 0; k < SPLITK2; ++k)
            s += part[(size_t)k * (Pn * Cn) + (size_t)n * Cn + c];
        size_t idx = (size_t)n * Cn + c;
        out1[idx] = wsum[idx] + (upd ? s : 0.f);
    }
}

extern "C" void kernel_launch(void* const* d_in, const int* in_sizes, int n_in,
                              void* d_out, int out_size, void* d_ws, size_t ws_size,
                              hipStream_t stream) {
    const float* fm    = (const float*)d_in[0];
    const float* emb   = (const float*)d_in[1];
    const float* w     = (const float*)d_in[2];
    const float* wsum  = (const float*)d_in[3];
    const float* wnum  = (const float*)d_in[4];
    const int*   epoch = (const int*)d_in[5];
    float* out = (float*)d_out;
    float* wsf = (float*)d_ws;

    _Float16*       xmb   = (_Float16*)(wsf + OFF_XM);
    float*          partb = wsf + OFF_PART;          // alias of xm (xm dead before GEMM2)
    unsigned short* xtb   = (unsigned short*)(wsf + OFF_XT);
    unsigned short* atb   = (unsigned short*)(wsf + OFF_AT);
    _Float16*       wfb   = (_Float16*)(wsf + OFF_WF);
    float*          wnormb = wsf + OFF_WNORM;
    float*          rawpb  = wsf + OFF_RAWP;
    float*          meanb  = wsf + OFF_MEAN;

    k_wnorm<<<512, 64, 0, stream>>>(w, wnormb, wfb);
    k_prep2<<<dim3(Bn, 8), 512, 0, stream>>>(fm, xmb, xtb);
    k_post<<<256, 512, 0, stream>>>(xmb, wfb, wnormb, atb, rawpb);
    k_reduce<<<2, 256, 0, stream>>>(rawpb, wnum, meanb, out + OUT_WNUM);
    k_cvec<<<Bn, 256, 0, stream>>>(rawpb, w, emb, epoch, out + OUT_CAT);
    k_upw_mfma<<<dim3(4, 4, SPLITK2), 256, 0, stream>>>(atb, xtb, partb);
    k_wep<<<Pn, 256, 0, stream>>>(partb, meanb, wsum, out + OUT_WSUM);
}

// Round 6
// 193.971 us; speedup vs baseline: 2.7049x; 1.0178x over previous
//
#include <hip/hip_runtime.h>
#include <hip/hip_bf16.h>

// Problem constants
// B=128, C=512, H=W=14 -> HW=196, M=B*HW=25088, P=512
#define Bn   128
#define Cn   512
#define HWn  196
#define Mn   25088
#define Pn   512
#define MPAD 32768         // padded m': b*256 + chunk*64 + j (chunk=hw/49, j=hw%49)
#define SPLITK2 32         // GEMM2 split-K chunks of 1024 m'
#define KCH  1024

// ws layout (float offsets)
#define OFF_XT     0u          // bf16 [512][32768] = 8,388,608 f
#define OFF_AT     8388608u    // bf16 [512][32768] = 8,388,608 f
#define OFF_PART   16777216u   // 32*512*512 fp32 = 8,388,608 f
#define OFF_XM     16777216u   // fp16 [M][C] = 6,422,528 f (alias PART: xm dead before GEMM2)
#define OFF_WF     25165824u   // fp16 [512][512] = 131,072 f
#define OFF_WNORM  25296896u   // 512
#define OFF_RAWP   25297408u   // 256*512 = 131,072
#define OFF_MEAN   25428480u   // 512
// total = 25,428,992 floats = 101.7 MB  (<= 103.6 MB proven in round 4)

// d_out layout (float offsets)
#define OUT_CAT  0u        // 128*1024
#define OUT_WSUM 131072u   // 512*512
#define OUT_WNUM 393216u   // 512

using bf16x8 = __attribute__((ext_vector_type(8))) short;
using f16x8  = __attribute__((ext_vector_type(8))) _Float16;
using f32x4  = __attribute__((ext_vector_type(4))) float;

__device__ __forceinline__ unsigned short f2b(float f) {
    union { float f; unsigned u; } x; x.f = f;
    unsigned r = x.u + 0x7fffu + ((x.u >> 16) & 1u);   // RNE
    return (unsigned short)(r >> 16);
}

// ---------------- wnorm: ||w_n||^2  + w -> fp16 [N][C] ----------------
__global__ __launch_bounds__(64) void k_wnorm(const float* __restrict__ w,
                                              float* __restrict__ wn,
                                              _Float16* __restrict__ wf) {
    int n = blockIdx.x, l = threadIdx.x;
    const float* p = w + (size_t)n * Cn + l * 8;
    float4 a = *(const float4*)p;
    float4 b = *(const float4*)(p + 4);
    float s = a.x*a.x + a.y*a.y + a.z*a.z + a.w*a.w
            + b.x*b.x + b.y*b.y + b.z*b.z + b.w*b.w;
    alignas(16) _Float16 h[8];
    h[0]=(_Float16)a.x; h[1]=(_Float16)a.y; h[2]=(_Float16)a.z; h[3]=(_Float16)a.w;
    h[4]=(_Float16)b.x; h[5]=(_Float16)b.y; h[6]=(_Float16)b.z; h[7]=(_Float16)b.w;
    *(float4*)(wf + (size_t)n * Cn + l * 8) = *(const float4*)h;
    #pragma unroll
    for (int o = 32; o > 0; o >>= 1) s += __shfl_down(s, o);
    if (l == 0) wn[n] = s;
}

// ------- prep2: fm fp32 [b][c][hw] -> xm fp16 [m][c]  AND xt bf16 [c][m'] -
__global__ __launch_bounds__(512) void k_prep2(const float* __restrict__ fm,
                                               _Float16* __restrict__ xm,
                                               unsigned short* __restrict__ xt) {
    __shared__ _Float16 tile[64][200];
    int b = blockIdx.x;
    int cg = blockIdx.y * 64;
    int t = threadIdx.x;
    // load 64 c-rows x 196 hw (49 float4 each)
    for (int i = t; i < 64 * 49; i += 512) {
        int cl = i / 49, h4 = i - cl * 49;
        float4 v = *(const float4*)(fm + ((size_t)(b * Cn + cg + cl) * HWn) + h4 * 4);
        tile[cl][h4*4+0] = (_Float16)v.x;
        tile[cl][h4*4+1] = (_Float16)v.y;
        tile[cl][h4*4+2] = (_Float16)v.z;
        tile[cl][h4*4+3] = (_Float16)v.w;
    }
    __syncthreads();
    // xm: transposed fp16 [m][c]
    for (int i = t; i < HWn * 8; i += 512) {
        int hw = i >> 3, seg = i & 7;
        alignas(16) _Float16 h[8];
        #pragma unroll
        for (int j = 0; j < 8; ++j) h[j] = tile[seg * 8 + j][hw];
        *(float4*)(xm + (size_t)(b * HWn + hw) * Cn + cg + seg * 8) = *(const float4*)h;
    }
    // xt: bf16 [c][b*256 + q*64 + j], j<49 valid, 49..63 zero
    for (int i = t; i < 64 * 4 * 16; i += 512) {
        int cl = i >> 6, rem = i & 63;
        int q = rem >> 4, j4 = rem & 15;
        ushort4 o;
        if (j4 < 12) {
            o.x = f2b((float)tile[cl][q*49 + j4*4 + 0]);
            o.y = f2b((float)tile[cl][q*49 + j4*4 + 1]);
            o.z = f2b((float)tile[cl][q*49 + j4*4 + 2]);
            o.w = f2b((float)tile[cl][q*49 + j4*4 + 3]);
        } else if (j4 == 12) {
            o.x = f2b((float)tile[cl][q*49 + 48]);
            o.y = 0; o.z = 0; o.w = 0;
        } else {
            o.x = 0; o.y = 0; o.z = 0; o.w = 0;
        }
        *(ushort4*)(xt + (size_t)(cg + cl) * MPAD + b * 256 + q * 64 + j4 * 4) = o;
    }
}

// --- k_post: fused GEMM1(fp16 MFMA) + softmax + threshold + at + colsums --
// grid 256: block = (b, half) -> 98 rows x all 512 n. 8 waves (2 mq x 4 nq).
__global__ __launch_bounds__(512, 2) void k_post(const _Float16* __restrict__ xm,
                                                 const _Float16* __restrict__ wf,
                                                 const float* __restrict__ wnorm,
                                                 unsigned short* __restrict__ at,
                                                 float* __restrict__ rawp) {
    __shared__ _Float16 As[113][72];     // 144B row stride -> 2-way (free) on frag reads
    __shared__ float red[2][64][4];
    __shared__ float colp[2][512];
    const int bid = blockIdx.x;
    const int b = bid >> 1, half = bid & 1;
    const int tid = threadIdx.x;
    const int wave = tid >> 6, lane = tid & 63;
    const int mq = wave >> 2, nq = wave & 3;
    const int rl = lane & 15, rq = lane >> 4;
    const int kb = rq * 8;
    const int m0 = b * 196 + half * 98;
    const int n0 = nq * 128;
    const int srow = tid >> 2;
    const int sk16 = (tid & 3) * 8;

    const _Float16* bp[8];
    #pragma unroll
    for (int g = 0; g < 8; ++g)
        bp[g] = wf + (size_t)(n0 + g * 16 + rl) * Cn + kb;

    f32x4 acc[4][8] = {};
    for (int c = 0; c < 8; ++c) {
        const int k0 = c * 64;
        __syncthreads();
        if (srow < 113) {
            const _Float16* src = xm + (size_t)(m0 + srow) * Cn + k0 + sk16;
            f16x8 v0 = *(const f16x8*)src;
            f16x8 v1 = *(const f16x8*)(src + 32);
            *(f16x8*)&As[srow][sk16]      = v0;
            *(f16x8*)&As[srow][32 + sk16] = v1;
        }
        __syncthreads();
        #pragma unroll
        for (int ks = 0; ks < 2; ++ks) {
            f16x8 a[4], bb[8];
            #pragma unroll
            for (int f = 0; f < 4; ++f)
                a[f] = *(const f16x8*)&As[mq * 49 + f * 16 + rl][ks * 32 + kb];
            #pragma unroll
            for (int g = 0; g < 8; ++g)
                bb[g] = *(const f16x8*)(bp[g] + k0 + ks * 32);
            #pragma unroll
            for (int f = 0; f < 4; ++f)
                #pragma unroll
                for (int g = 0; g < 8; ++g)
                    acc[f][g] = __builtin_amdgcn_mfma_f32_16x16x32_f16(a[f], bb[g], acc[f][g], 0, 0, 0);
        }
    }
    // scores: 2*dot - ||w||^2
    float wn[8];
    #pragma unroll
    for (int g = 0; g < 8; ++g) wn[g] = wnorm[n0 + g * 16 + rl];
    #pragma unroll
    for (int f = 0; f < 4; ++f)
        #pragma unroll
        for (int g = 0; g < 8; ++g)
            #pragma unroll
            for (int r = 0; r < 4; ++r)
                acc[f][g][r] = 2.0f * acc[f][g][r] - wn[g];
    // row max across block
    float mx[4][4];
    #pragma unroll
    for (int f = 0; f < 4; ++f)
        #pragma unroll
        for (int r = 0; r < 4; ++r) {
            float m_ = acc[f][0][r];
            #pragma unroll
            for (int g = 1; g < 8; ++g) m_ = fmaxf(m_, acc[f][g][r]);
            #pragma unroll
            for (int o = 8; o >= 1; o >>= 1) m_ = fmaxf(m_, __shfl_xor(m_, o));
            mx[f][r] = m_;
        }
    if (rl == 0)
        #pragma unroll
        for (int f = 0; f < 4; ++f)
            #pragma unroll
            for (int r = 0; r < 4; ++r)
                red[mq][f * 16 + rq * 4 + r][nq] = mx[f][r];
    __syncthreads();
    float rmax[4][4];
    #pragma unroll
    for (int f = 0; f < 4; ++f)
        #pragma unroll
        for (int r = 0; r < 4; ++r) {
            float* q = red[mq][f * 16 + rq * 4 + r];
            rmax[f][r] = fmaxf(fmaxf(q[0], q[1]), fmaxf(q[2], q[3]));
        }
    // exp + row sums
    float sm[4][4];
    #pragma unroll
    for (int f = 0; f < 4; ++f)
        #pragma unroll
        for (int r = 0; r < 4; ++r) {
            float s_ = 0.f;
            #pragma unroll
            for (int g = 0; g < 8; ++g) {
                float p = __expf(acc[f][g][r] - rmax[f][r]);
                acc[f][g][r] = p;
                s_ += p;
            }
            #pragma unroll
            for (int o = 8; o >= 1; o >>= 1) s_ += __shfl_xor(s_, o);
            sm[f][r] = s_;
        }
    __syncthreads();
    if (rl == 0)
        #pragma unroll
        for (int f = 0; f < 4; ++f)
            #pragma unroll
            for (int r = 0; r < 4; ++r)
                red[mq][f * 16 + rq * 4 + r][nq] = sm[f][r];
    __syncthreads();
    const float invP = 1.0f / 512.0f;
    #pragma unroll
    for (int f = 0; f < 4; ++f)
        #pragma unroll
        for (int r = 0; r < 4; ++r) {
            float* q = red[mq][f * 16 + rq * 4 + r];
            float inv = 1.0f / (q[0] + q[1] + q[2] + q[3]);
            #pragma unroll
            for (int g = 0; g < 8; ++g) {
                float a = acc[f][g][r] * inv;
                acc[f][g][r] = (a < invP) ? 0.0f : a;
            }
        }
    // column sums over valid rows (mloc < 49)
    float cs[8] = {};
    #pragma unroll
    for (int g = 0; g < 8; ++g) {
        #pragma unroll
        for (int f = 0; f < 4; ++f)
            #pragma unroll
            for (int r = 0; r < 4; ++r)
                if (f * 16 + rq * 4 + r < 49) cs[g] += acc[f][g][r];
        cs[g] += __shfl_xor(cs[g], 16);
        cs[g] += __shfl_xor(cs[g], 32);
    }
    if (rq == 0)
        #pragma unroll
        for (int g = 0; g < 8; ++g) colp[mq][n0 + g * 16 + rl] = cs[g];
    __syncthreads();
    if (tid < 512) rawp[(size_t)bid * 512 + tid] = colp[0][tid] + colp[1][tid];
    // at write: bf16 [n][b*256 + chunk*64 + mloc], pad rows 49..63 = 0
    const int mb = b * 256 + (half * 2 + mq) * 64;
    #pragma unroll
    for (int f = 0; f < 4; ++f) {
        const int mloc = f * 16 + rq * 4;
        #pragma unroll
        for (int g = 0; g < 8; ++g) {
            ushort4 o;
            o.x = (mloc + 0 < 49) ? f2b(acc[f][g][0]) : (unsigned short)0;
            o.y = (mloc + 1 < 49) ? f2b(acc[f][g][1]) : (unsigned short)0;
            o.z = (mloc + 2 < 49) ? f2b(acc[f][g][2]) : (unsigned short)0;
            o.w = (mloc + 3 < 49) ? f2b(acc[f][g][3]) : (unsigned short)0;
            *(ushort4*)(at + (size_t)(n0 + g * 16 + rl) * MPAD + mb + mloc) = o;
        }
    }
}

// ---------------- assign_mean + new_w_ep_num ----------------
__global__ __launch_bounds__(256) void k_reduce(const float* __restrict__ rawp,
                                                const float* __restrict__ wnum,
                                                float* __restrict__ mean,
                                                float* __restrict__ outnum) {
    int n = blockIdx.x * 256 + threadIdx.x;
    float s = 0.f;
    for (int r = 0; r < 256; ++r) s += rawp[(size_t)r * Pn + n];
    mean[n] = s;
    outnum[n] = wnum[n] + (s > 1.0f ? s : 0.0f);
}

// ---------------- cvec + concat ----------------
__global__ __launch_bounds__(256) void k_cvec(const float* __restrict__ rawp,
                                              const float* __restrict__ w,
                                              const float* __restrict__ emb,
                                              const int* __restrict__ epoch,
                                              float* __restrict__ out) {
    __shared__ float srow[512];
    int b = blockIdx.x, t = threadIdx.x;
    srow[t]       = rawp[(size_t)(2*b) * Pn + t]       + rawp[(size_t)(2*b+1) * Pn + t];
    srow[t + 256] = rawp[(size_t)(2*b) * Pn + t + 256] + rawp[(size_t)(2*b+1) * Pn + t + 256];
    __syncthreads();
    float a0 = 0.f, a1 = 0.f;
    for (int p = 0; p < Pn; ++p) {
        float ap = srow[p];
        a0 = fmaf(ap, w[(size_t)p * Cn + t], a0);
        a1 = fmaf(ap, w[(size_t)p * Cn + t + 256], a1);
    }
    const float sc = 1.0f / (196.0f * 512.0f);
    int ep = epoch[0];
    float c0 = (ep > 2) ? fmaxf(a0, 0.f) * sc : 0.f;
    float c1 = (ep > 2) ? fmaxf(a1, 0.f) * sc : 0.f;
    out[(size_t)b * 1024 + t]             = emb[(size_t)b * Cn + t];
    out[(size_t)b * 1024 + t + 256]       = emb[(size_t)b * Cn + t + 256];
    out[(size_t)b * 1024 + 512 + t]       = c0;
    out[(size_t)b * 1024 + 512 + t + 256] = c1;
}

// ---------------- GEMM2 (MFMA): update_w[n][c] = sum_m' at[n][m']*xt[c][m']
// 1-D grid 512, z-major swizzle: id = z + 32*m  (m = x + 4*y)
// -> all 16 (x,y) tiles of one K-chunk z land on the same XCD (id%8 const)
__global__ __launch_bounds__(256) void k_upw_mfma(const unsigned short* __restrict__ at,
                                                  const unsigned short* __restrict__ xt,
                                                  float* __restrict__ part) {
    int id = blockIdx.x;
    int sp = id & 31;          // K-chunk
    int m  = id >> 5;          // 0..15
    int tid = threadIdx.x;
    int wave = tid >> 6, lane = tid & 63;
    int wn = wave >> 1, wc = wave & 1;
    int n0 = (m & 3) * 128 + wn * 64;
    int c0 = (m >> 2) * 128 + wc * 64;
    int mbase = sp * KCH + (lane >> 4) * 8;
    int rl = lane & 15;
    const unsigned short* ap[4];
    const unsigned short* bp[4];
    #pragma unroll
    for (int f = 0; f < 4; ++f) {
        ap[f] = at + (size_t)(n0 + f * 16 + rl) * MPAD + mbase;
        bp[f] = xt + (size_t)(c0 + f * 16 + rl) * MPAD + mbase;
    }
    f32x4 acc[4][4] = {};
    for (int ks = 0; ks < KCH / 32; ++ks) {
        bf16x8 a[4], b[4];
        #pragma unroll
        for (int f = 0; f < 4; ++f) {
            a[f] = *(const bf16x8*)(ap[f] + ks * 32);
            b[f] = *(const bf16x8*)(bp[f] + ks * 32);
        }
        #pragma unroll
        for (int i = 0; i < 4; ++i)
            #pragma unroll
            for (int j = 0; j < 4; ++j)
                acc[i][j] = __builtin_amdgcn_mfma_f32_16x16x32_bf16(a[i], b[j], acc[i][j], 0, 0, 0);
    }
    float* o = part + (size_t)sp * (Pn * Cn);
    int rq = (lane >> 4) * 4;
    #pragma unroll
    for (int i = 0; i < 4; ++i) {
        #pragma unroll
        for (int j = 0; j < 4; ++j) {
            int n = n0 + i * 16 + rq;
            int c = c0 + j * 16 + rl;
            #pragma unroll
            for (int r = 0; r < 4; ++r)
                o[(size_t)(n + r) * Cn + c] = acc[i][j][r];
        }
    }
}

// ---------------- epilogue: new_w_ep_sum ----------------
__global__ __launch_bounds__(256) void k_wep(const float* __restrict__ part,
                                             const float* __restrict__ mean,
                                             const float* __restrict__ wsum,
                                             float* __restrict__ out1) {
    int n = blockIdx.x, t = threadIdx.x;
    bool upd = mean[n] > 1.0f;
    #pragma unroll
    for (int cc = 0; cc < 2; ++cc) {
        int c = t + cc * 256;
        float s = 0.f;
        #pragma unroll
        for (int k = 0; k < SPLITK2; ++k)
            s += part[(size_t)k * (Pn * Cn) + (size_t)n * Cn + c];
        size_t idx = (size_t)n * Cn + c;
        out1[idx] = wsum[idx] + (upd ? s : 0.f);
    }
}

extern "C" void kernel_launch(void* const* d_in, const int* in_sizes, int n_in,
                              void* d_out, int out_size, void* d_ws, size_t ws_size,
                              hipStream_t stream) {
    const float* fm    = (const float*)d_in[0];
    const float* emb   = (const float*)d_in[1];
    const float* w     = (const float*)d_in[2];
    const float* wsum  = (const float*)d_in[3];
    const float* wnum  = (const float*)d_in[4];
    const int*   epoch = (const int*)d_in[5];
    float* out = (float*)d_out;
    float* wsf = (float*)d_ws;

    unsigned short* xtb   = (unsigned short*)(wsf + OFF_XT);
    unsigned short* atb   = (unsigned short*)(wsf + OFF_AT);
    float*          partb = wsf + OFF_PART;
    _Float16*       xmb   = (_Float16*)(wsf + OFF_XM);   // alias of part (xm dead before GEMM2)
    _Float16*       wfb   = (_Float16*)(wsf + OFF_WF);
    float*          wnormb = wsf + OFF_WNORM;
    float*          rawpb  = wsf + OFF_RAWP;
    float*          meanb  = wsf + OFF_MEAN;

    k_wnorm<<<512, 64, 0, stream>>>(w, wnormb, wfb);
    k_prep2<<<dim3(Bn, 8), 512, 0, stream>>>(fm, xmb, xtb);
    k_post<<<256, 512, 0, stream>>>(xmb, wfb, wnormb, atb, rawpb);
    k_reduce<<<2, 256, 0, stream>>>(rawpb, wnum, meanb, out + OUT_WNUM);
    k_cvec<<<Bn, 256, 0, stream>>>(rawpb, w, emb, epoch, out + OUT_CAT);
    k_upw_mfma<<<512, 256, 0, stream>>>(atb, xtb, partb);
    k_wep<<<Pn, 256, 0, stream>>>(partb, meanb, wsum, out + OUT_WSUM);
}